// Round 8
// baseline (383.256 us; speedup 1.0000x reference)
//
#include <hip/hip_runtime.h>
#include <hip/hip_cooperative_groups.h>
#include <math.h>

namespace cg = cooperative_groups;

#define Nn 8192
#define Dd 256
#define NBINS 64

typedef __attribute__((ext_vector_type(8))) short short8;
typedef __attribute__((ext_vector_type(4))) float f32x4;

#define GLOAD16(g, l)                                                        \
  __builtin_amdgcn_global_load_lds(                                          \
      (const __attribute__((address_space(1))) void*)(g),                    \
      (__attribute__((address_space(3))) void*)(l), 16, 0, 0)

static __device__ __forceinline__ unsigned short f2bf(float f) {
  unsigned int u = __float_as_uint(f);
  u = (u + 0x7fffu + ((u >> 16) & 1u)) >> 16;  // RNE
  return (unsigned short)u;
}
// order-preserving bijection float -> uint (atomicMax/Min on uint handles negatives)
static __device__ __forceinline__ unsigned int enc_ord(float f) {
  unsigned int u = __float_as_uint(f);
  return (u & 0x80000000u) ? ~u : (u | 0x80000000u);
}
static __device__ __forceinline__ float dec_ord(unsigned int u) {
  unsigned int b2 = (u & 0x80000000u) ? (u ^ 0x80000000u) : ~u;
  return __uint_as_float(b2);
}

// stage one half-K tile (128 cols x 128 k = 32KB), XOR chunk placement:
// chunk c holds (col=c>>4, kq=(c&15)^(col&15)) -> coalesced global src, conflict-free reads
static __device__ __forceinline__ void stage_half(const unsigned short* __restrict__ xb,
                                                  int c0, int hh, unsigned short* buf, int t) {
#pragma unroll
  for (int i = 0; i < 4; ++i) {
    const int c = i * 512 + t;
    const int col = c >> 4;
    const int kq = (c & 15) ^ (col & 15);
    GLOAD16(xb + (size_t)(c0 + col) * Dd + hh * 128 + kq * 8, buf + (size_t)c * 8);
  }
}

__global__ __launch_bounds__(512, 2) void fused_kernel(
    const float* __restrict__ x, const int* __restrict__ targets,
    float* __restrict__ out, unsigned short* __restrict__ xb,
    float2* __restrict__ sqlab, unsigned int* __restrict__ pos2,
    unsigned int* __restrict__ neg2, float* __restrict__ hv_g,
    unsigned int* __restrict__ gmm) {
  __shared__ __align__(16) unsigned short Us[2 * 2048 * 8];  // 64KB: A stage, then B dbuf
  __shared__ __align__(16) float2 sl_s[2048];                // 16KB (sq,label) for col split
  __shared__ int lab_s[128];
  __shared__ float hist_w[8][NBINS];
  __shared__ float cdf_s[NBINS];
  __shared__ float rbuf[8];

  const int t = threadIdx.x;   // 0..511
  const int b = blockIdx.x;    // 0..255
  const int lane = t & 63;
  const int wv = t >> 6;

  // ================= P0: bf16 cast + row norms + init =================
  {
    const int row = b * 32 + (t >> 4);
    const float* xr = x + (size_t)row * Dd + (t & 15) * 16;
    const float4 v0 = ((const float4*)xr)[0];
    const float4 v1 = ((const float4*)xr)[1];
    const float4 v2 = ((const float4*)xr)[2];
    const float4 v3 = ((const float4*)xr)[3];
    short8 o0, o1;
    o0[0] = (short)f2bf(v0.x); o0[1] = (short)f2bf(v0.y);
    o0[2] = (short)f2bf(v0.z); o0[3] = (short)f2bf(v0.w);
    o0[4] = (short)f2bf(v1.x); o0[5] = (short)f2bf(v1.y);
    o0[6] = (short)f2bf(v1.z); o0[7] = (short)f2bf(v1.w);
    o1[0] = (short)f2bf(v2.x); o1[1] = (short)f2bf(v2.y);
    o1[2] = (short)f2bf(v2.z); o1[3] = (short)f2bf(v2.w);
    o1[4] = (short)f2bf(v3.x); o1[5] = (short)f2bf(v3.y);
    o1[6] = (short)f2bf(v3.z); o1[7] = (short)f2bf(v3.w);
    short8* xw = (short8*)(xb + (size_t)row * Dd + (t & 15) * 16);
    xw[0] = o0; xw[1] = o1;
    float s = v0.x * v0.x + v0.y * v0.y + v0.z * v0.z + v0.w * v0.w +
              v1.x * v1.x + v1.y * v1.y + v1.z * v1.z + v1.w * v1.w +
              v2.x * v2.x + v2.y * v2.y + v2.z * v2.z + v2.w * v2.w +
              v3.x * v3.x + v3.y * v3.y + v3.z * v3.z + v3.w * v3.w;
#pragma unroll
    for (int off = 8; off >= 1; off >>= 1) s += __shfl_xor(s, off);
    if ((t & 15) == 0) {
      sqlab[row] = make_float2(s, __int_as_float(targets[row]));
      pos2[row] = 0x007fffffu;  // enc_ord(-inf)
      neg2[row] = 0xff800000u;  // enc_ord(+inf)
    }
    if (b == 0 && t == 0) { gmm[0] = 0x007fffffu; gmm[1] = 0xff800000u; }
  }
  __threadfence();
  cg::this_grid().sync();
  __threadfence();

  // ================= P1: MFMA Gram + fused masked max/min (r5-proven pipeline) =================
  {
    const int w = wv;
    const int wr = w >> 2, wc = w & 3;  // 2 row-halves x 4 col-quarters
    const int c_l = lane & 15;
    const int kq_l = lane >> 4;
    const int rows0 = (b & 63) * 128;
    const int cbase = (b >> 6) * 2048;  // 4 col splits, 16 ct of 128 cols

    // stage A (both K halves) into Us; stage sl_s + labels
    stage_half(xb, rows0, 0, Us, t);
    stage_half(xb, rows0, 1, Us + 2048 * 8, t);
#pragma unroll
    for (int i = 0; i < 4; ++i) {
      const int j = i * 512 + t;
      sl_s[j] = sqlab[cbase + j];
    }
    if (t < 128) lab_s[t] = __float_as_int(sqlab[rows0 + t].y);
    __syncthreads();  // A staged (implicit vmcnt(0))

    // A fragments -> registers for the whole phase (forced residency: Us gets overwritten)
    const short8* Uv = (const short8*)Us;
    short8 af[32];
#pragma unroll
    for (int k2 = 0; k2 < 8; ++k2)
#pragma unroll
      for (int m = 0; m < 4; ++m) {
        const int kqf = k2 * 4 + kq_l;
        const int rl = wr * 64 + m * 16 + c_l;
        af[k2 * 4 + m] = Uv[(kqf >> 4) * 2048 + rl * 16 + ((kqf & 15) ^ (rl & 15))];
      }
    int labp[8];
#pragma unroll
    for (int m = 0; m < 4; ++m)
#pragma unroll
      for (int pp = 0; pp < 2; ++pp) {
        const int r0 = wr * 64 + m * 16 + kq_l * 4 + 2 * pp;
        labp[m * 2 + pp] = (lab_s[r0] & 0xffff) | (lab_s[r0 + 1] << 16);
      }
    __syncthreads();  // af/lab reads done before B dbuf overwrites Us

    unsigned short* Bs0 = Us;
    unsigned short* Bs1 = Us + 2048 * 8;
    const short8* Bv0 = (const short8*)Bs0;
    const short8* Bv1 = (const short8*)Bs1;

    stage_half(xb, cbase, 0, Bs0, t);  // prefetch first half-tile

    const int cc0 = wc * 32 + c_l;
    const int cc1 = wc * 32 + 16 + c_l;
    float pmax[16], nmin[16];
#pragma unroll
    for (int i = 0; i < 16; ++i) { pmax[i] = -INFINITY; nmin[i] = INFINITY; }

#pragma unroll 1
    for (int ct = 0; ct < 16; ++ct) {
      const int c0 = cbase + ct * 128;
      f32x4 acc[4][2];
#pragma unroll
      for (int m = 0; m < 4; ++m)
#pragma unroll
        for (int n = 0; n < 2; ++n) acc[m][n] = (f32x4){0.f, 0.f, 0.f, 0.f};

      // ---- half 0: compute Bs0, prefetch Bs1 ----
      __syncthreads();  // Bs0 staged (loads issued one phase ago); WAR-protects Bs1
      stage_half(xb, c0, 1, Bs1, t);
#pragma unroll
      for (int ks = 0; ks < 4; ++ks) {
        short8 bf0 = Bv0[cc0 * 16 + ((ks * 4 + kq_l) ^ (cc0 & 15))];
        short8 bf1 = Bv0[cc1 * 16 + ((ks * 4 + kq_l) ^ (cc1 & 15))];
#pragma unroll
        for (int m = 0; m < 4; ++m) {
          acc[m][0] = __builtin_amdgcn_mfma_f32_16x16x32_bf16(af[ks * 4 + m], bf0, acc[m][0], 0, 0, 0);
          acc[m][1] = __builtin_amdgcn_mfma_f32_16x16x32_bf16(af[ks * 4 + m], bf1, acc[m][1], 0, 0, 0);
        }
      }

      // ---- half 1: compute Bs1, prefetch next ct's Bs0 ----
      __syncthreads();  // Bs1 staged; WAR-protects Bs0
      if (ct < 15) stage_half(xb, c0 + 128, 0, Bs0, t);
#pragma unroll
      for (int ks = 0; ks < 4; ++ks) {
        short8 bf0 = Bv1[cc0 * 16 + ((ks * 4 + kq_l) ^ (cc0 & 15))];
        short8 bf1 = Bv1[cc1 * 16 + ((ks * 4 + kq_l) ^ (cc1 & 15))];
#pragma unroll
        for (int m = 0; m < 4; ++m) {
          acc[m][0] = __builtin_amdgcn_mfma_f32_16x16x32_bf16(af[(4 + ks) * 4 + m], bf0, acc[m][0], 0, 0, 0);
          acc[m][1] = __builtin_amdgcn_mfma_f32_16x16x32_bf16(af[(4 + ks) * 4 + m], bf1, acc[m][1], 0, 0, 0);
        }
      }

      // ---- epilogue: masked running max/min on g = sq_c - 2*acc ----
      {
        const float2 sl0 = sl_s[ct * 128 + cc0];
        const float2 sl1 = sl_s[ct * 128 + cc1];
#pragma unroll
        for (int n = 0; n < 2; ++n) {
          const float sc = (n == 0) ? sl0.x : sl1.x;
          const int lc = __float_as_int((n == 0) ? sl0.y : sl1.y);
#pragma unroll
          for (int idx = 0; idx < 16; ++idx) {
            const int m = idx >> 2, q = idx & 3;
            const float g = fmaf(-2.0f, acc[m][n][q], sc);
            const int lr = (labp[idx >> 1] >> ((idx & 1) * 16)) & 0xffff;
            const bool same = (lr == lc);
            pmax[idx] = same ? fmaxf(pmax[idx], g) : pmax[idx];
            nmin[idx] = same ? nmin[idx] : fminf(nmin[idx], g);
          }
        }
      }
    }

    // reduce over 16 col-lanes, 2 atomics per row
#pragma unroll
    for (int i = 0; i < 16; ++i) {
      float p = pmax[i], nn2 = nmin[i];
#pragma unroll
      for (int off = 1; off < 16; off <<= 1) {
        p = fmaxf(p, __shfl_xor(p, off));
        nn2 = fminf(nn2, __shfl_xor(nn2, off));
      }
      if (c_l == 0) {
        const int rowg = rows0 + wr * 64 + (i >> 2) * 16 + kq_l * 4 + (i & 3);
        atomicMax(&pos2[rowg], enc_ord(p));
        atomicMin(&neg2[rowg], enc_ord(nn2));
      }
    }
  }
  __threadfence();
  cg::this_grid().sync();
  __threadfence();

  // ================= P2: hv + global extremes =================
  if (t < 32) {
    const int i2 = b * 32 + t;
    const float sv = sqlab[i2].x;
    const unsigned int pv = __hip_atomic_load(&pos2[i2], __ATOMIC_RELAXED, __HIP_MEMORY_SCOPE_AGENT);
    const unsigned int nv = __hip_atomic_load(&neg2[i2], __ATOMIC_RELAXED, __HIP_MEMORY_SCOPE_AGENT);
    const float p2v = fmaxf(sv + dec_ord(pv), 1e-12f);
    const float n2v = fmaxf(sv + dec_ord(nv), 1e-12f);
    const float hv = sqrtf(p2v) - sqrtf(n2v);
    hv_g[i2] = hv;
    float lmax = hv, lmin = hv;
#pragma unroll
    for (int off = 16; off >= 1; off >>= 1) {
      lmax = fmaxf(lmax, __shfl_xor(lmax, off));
      lmin = fminf(lmin, __shfl_xor(lmin, off));
    }
    if (t == 0) {
      atomicMax(&gmm[0], enc_ord(lmax));
      atomicMin(&gmm[1], enc_ord(lmin));
    }
  }
  __threadfence();
  cg::this_grid().sync();
  __threadfence();

  // ================= P3: histogram, cdf, loss (block 0 only) =================
  if (b != 0) return;
  hist_w[wv][lane] = 0.0f;
  const unsigned int gmx = __hip_atomic_load(&gmm[0], __ATOMIC_RELAXED, __HIP_MEMORY_SCOPE_AGENT);
  const unsigned int gmn = __hip_atomic_load(&gmm[1], __ATOMIC_RELAXED, __HIP_MEMORY_SCOPE_AGENT);
  const float maxv = fmaxf(dec_ord(gmx), 2.0f);
  const float minv = fminf(dec_ord(gmn), -2.0f);
  const float bw = (maxv - minv) / (float)(NBINS - 1);
  __syncthreads();

  for (int i = t; i < Nn; i += 512) {
    const float hv = hv_g[i];
    int lo = (int)floorf((hv - minv) / bw);
    lo = min(max(lo, 0), NBINS - 1);
    const int hi = min(lo + 1, NBINS - 1);
    const float alpha = 1.0f - (hv - minv - (float)lo * bw) / bw;
    atomicAdd(&hist_w[wv][lo], alpha);
    atomicAdd(&hist_w[wv][hi], 1.0f - alpha);
  }
  __syncthreads();

  if (t < NBINS) {
    float h = 0.0f;
#pragma unroll
    for (int w2 = 0; w2 < 8; ++w2) h += hist_w[w2][t];
    float total = h;
#pragma unroll
    for (int off = 32; off >= 1; off >>= 1) total += __shfl_xor(total, off);
    const float hn = h / (total + 1e-6f);
    float s2 = hn;
#pragma unroll
    for (int off = 32; off >= 1; off >>= 1) s2 += __shfl_xor(s2, off);
    const float pdf = hn / s2;
    float c = pdf;
#pragma unroll
    for (int off = 1; off < 64; off <<= 1) {
      const float u = __shfl_up(c, off);
      if (lane >= off) c += u;
    }
    cdf_s[t] = c;
  }
  __syncthreads();

  float acc2 = 0.0f;
  for (int i = t; i < Nn; i += 512) {
    const float hv = hv_g[i];
    int lo = (int)floorf((hv - minv) / bw);
    lo = min(max(lo, 0), NBINS - 1);
    acc2 += cdf_s[lo] * hv;
  }
#pragma unroll
  for (int off = 32; off >= 1; off >>= 1) acc2 += __shfl_xor(acc2, off);
  if (lane == 0) rbuf[wv] = acc2;
  __syncthreads();
  if (t == 0) {
    float s = 0.0f;
    for (int w2 = 0; w2 < 8; ++w2) s += rbuf[w2];
    out[0] = s / (float)Nn;
  }
}

// ---------------- launch ----------------
extern "C" void kernel_launch(void* const* d_in, const int* in_sizes, int n_in,
                              void* d_out, int out_size, void* d_ws, size_t ws_size,
                              hipStream_t stream) {
  const float* x = (const float*)d_in[0];
  const int* targets = (const int*)d_in[1];
  float* out = (float*)d_out;

  char* p = (char*)d_ws;
  unsigned short* xb = (unsigned short*)p;  p += (size_t)Nn * Dd * 2;  // 4MB
  float2* sqlab = (float2*)p;               p += (size_t)Nn * 8;
  unsigned int* pos2 = (unsigned int*)p;    p += (size_t)Nn * 4;
  unsigned int* neg2 = (unsigned int*)p;    p += (size_t)Nn * 4;
  float* hv_g = (float*)p;                  p += (size_t)Nn * 4;
  unsigned int* gmm = (unsigned int*)p;

  void* args[] = {&x, &targets, &out, &xb, &sqlab, &pos2, &neg2, &hv_g, &gmm};
  hipLaunchCooperativeKernel((void*)fused_kernel, dim3(256), dim3(512), args, 0, stream);
}

// Round 9
// 182.640 us; speedup vs baseline: 2.0984x; 2.0984x over previous
//
#include <hip/hip_runtime.h>
#include <math.h>

#define Nn 8192
#define Dd 256
#define NBINS 64
#define NSPLIT 8

typedef __attribute__((ext_vector_type(8))) short short8;
typedef __attribute__((ext_vector_type(4))) float f32x4;

#define GLOAD16(g, l)                                                        \
  __builtin_amdgcn_global_load_lds(                                          \
      (const __attribute__((address_space(1))) void*)(g),                    \
      (__attribute__((address_space(3))) void*)(l), 16, 0, 0)

static __device__ __forceinline__ unsigned short f2bf(float f) {
  unsigned int u = __float_as_uint(f);
  u = (u + 0x7fffu + ((u >> 16) & 1u)) >> 16;  // RNE
  return (unsigned short)u;
}
// order-preserving bijection float -> uint (atomicMax/Min on uint handles negatives)
static __device__ __forceinline__ unsigned int enc_ord(float f) {
  unsigned int u = __float_as_uint(f);
  return (u & 0x80000000u) ? ~u : (u | 0x80000000u);
}
static __device__ __forceinline__ float dec_ord(unsigned int u) {
  unsigned int b2 = (u & 0x80000000u) ? (u ^ 0x80000000u) : ~u;
  return __uint_as_float(b2);
}

// ---------------- K0: bf16 cast + fused (norm,label) + init accumulators ----------------
__global__ __launch_bounds__(256) void prep_kernel(const float* __restrict__ x,
                                                   const int* __restrict__ lab,
                                                   unsigned short* __restrict__ xb,
                                                   float2* __restrict__ sqlab,
                                                   unsigned int* __restrict__ pos2,
                                                   unsigned int* __restrict__ neg2,
                                                   unsigned int* __restrict__ gmm,
                                                   float* __restrict__ ghist,
                                                   float* __restrict__ ghsum) {
  const int w = threadIdx.x >> 6;
  const int lane = threadIdx.x & 63;
  const int row = blockIdx.x * 4 + w;
  const float4 v = *(const float4*)(x + (size_t)row * Dd + lane * 4);
  ushort4 b;
  b.x = f2bf(v.x); b.y = f2bf(v.y); b.z = f2bf(v.z); b.w = f2bf(v.w);
  *(ushort4*)(xb + (size_t)row * Dd + lane * 4) = b;
  float s = v.x * v.x + v.y * v.y + v.z * v.z + v.w * v.w;
#pragma unroll
  for (int off = 32; off >= 1; off >>= 1) s += __shfl_xor(s, off);
  if (lane == 0) {
    sqlab[row] = make_float2(s, __int_as_float(lab[row]));
    pos2[row] = 0x007fffffu;  // enc_ord(-inf)
    neg2[row] = 0xff800000u;  // enc_ord(+inf)
  }
  if (blockIdx.x == 0 && threadIdx.x < NBINS) {
    ghist[threadIdx.x] = 0.0f;
    ghsum[threadIdx.x] = 0.0f;
    if (threadIdx.x == 0) { gmm[0] = 0x007fffffu; gmm[1] = 0xff800000u; }
  }
}

// stage one half-K tile (128 cols x 128 k = 32KB), XOR chunk placement, 512 threads:
// chunk c holds (col=c>>4, kq=(c&15)^(col&15)) -> coalesced global src, conflict-free reads
static __device__ __forceinline__ void stage_half(const unsigned short* __restrict__ xb,
                                                  int c0, int hh, unsigned short* buf, int t) {
#pragma unroll
  for (int i = 0; i < 4; ++i) {
    const int c = i * 512 + t;
    const int col = c >> 4;
    const int kq = (c & 15) ^ (col & 15);
    GLOAD16(xb + (size_t)(c0 + col) * Dd + hh * 128 + kq * 8, buf + (size_t)c * 8);
  }
}

// epilogue half: masked running max/min on g = sq_c - 2*acc for column-fragment N
template <int N>
static __device__ __forceinline__ void epi_half(const f32x4 (&aP)[4][2], int ctp,
                                                const float2* sl_s, const int (&labp)[8],
                                                float (&pmax)[16], float (&nmin)[16],
                                                int cc0, int cc1) {
  const float2 sl = sl_s[ctp * 128 + (N ? cc1 : cc0)];
  const float sc = sl.x;
  const int lc = __float_as_int(sl.y);
#pragma unroll
  for (int idx = 0; idx < 16; ++idx) {
    const int m = idx >> 2, q = idx & 3;
    const float g = fmaf(-2.0f, aP[m][N][q], sc);
    const int lr = (labp[idx >> 1] >> ((idx & 1) * 16)) & 0xffff;
    const bool same = (lr == lc);
    pmax[idx] = same ? fmaxf(pmax[idx], g) : pmax[idx];
    nmin[idx] = same ? nmin[idx] : fminf(nmin[idx], g);
  }
}

// one ct tile: compute acc (cur) over both K halves; interleave epilogue of accP (prev ct)
// into the two MFMA windows (VALU overlaps the MFMA pipe; accP retired a barrier ago).
template <bool EPI>
static __device__ __forceinline__ void do_ct(
    f32x4 (&acc)[4][2], const f32x4 (&accP)[4][2], int ct, int cbase,
    const short8* Bv0, const short8* Bv1, unsigned short* Bs0, unsigned short* Bs1,
    const unsigned short* __restrict__ xb, const short8 (&af)[32], const int (&labp)[8],
    const float2* sl_s, float (&pmax)[16], float (&nmin)[16],
    int t, int cc0, int cc1, int kq_l) {
#pragma unroll
  for (int m = 0; m < 4; ++m)
#pragma unroll
    for (int n = 0; n < 2; ++n) acc[m][n] = (f32x4){0.f, 0.f, 0.f, 0.f};

  // ---- half 0: compute Bs0, prefetch Bs1; epi(prev, n=0) overlaps MFMA ----
  __syncthreads();  // Bs0 staged (loads issued one phase ago); WAR-protects Bs1
  stage_half(xb, cbase + ct * 128, 1, Bs1, t);
#pragma unroll
  for (int ks = 0; ks < 4; ++ks) {
    const short8 bf0 = Bv0[cc0 * 16 + ((ks * 4 + kq_l) ^ (cc0 & 15))];
    const short8 bf1 = Bv0[cc1 * 16 + ((ks * 4 + kq_l) ^ (cc1 & 15))];
#pragma unroll
    for (int m = 0; m < 4; ++m) {
      acc[m][0] = __builtin_amdgcn_mfma_f32_16x16x32_bf16(af[ks * 4 + m], bf0, acc[m][0], 0, 0, 0);
      acc[m][1] = __builtin_amdgcn_mfma_f32_16x16x32_bf16(af[ks * 4 + m], bf1, acc[m][1], 0, 0, 0);
    }
  }
  if (EPI) epi_half<0>(accP, ct - 1, sl_s, labp, pmax, nmin, cc0, cc1);

  // ---- half 1: compute Bs1, prefetch next ct's Bs0; epi(prev, n=1) overlaps ----
  __syncthreads();  // Bs1 staged; WAR-protects Bs0
  if (ct < 7) stage_half(xb, cbase + (ct + 1) * 128, 0, Bs0, t);
#pragma unroll
  for (int ks = 0; ks < 4; ++ks) {
    const short8 bf0 = Bv1[cc0 * 16 + ((ks * 4 + kq_l) ^ (cc0 & 15))];
    const short8 bf1 = Bv1[cc1 * 16 + ((ks * 4 + kq_l) ^ (cc1 & 15))];
#pragma unroll
    for (int m = 0; m < 4; ++m) {
      acc[m][0] = __builtin_amdgcn_mfma_f32_16x16x32_bf16(af[(4 + ks) * 4 + m], bf0, acc[m][0], 0, 0, 0);
      acc[m][1] = __builtin_amdgcn_mfma_f32_16x16x32_bf16(af[(4 + ks) * 4 + m], bf1, acc[m][1], 0, 0, 0);
    }
  }
  if (EPI) epi_half<1>(accP, ct - 1, sl_s, labp, pmax, nmin, cc0, cc1);
}

// ---------------- K1: MFMA Gram + fused masked max/min (2-deep acc pipeline) ----------------
__global__ __launch_bounds__(512, 2) void pairwise_kernel(const unsigned short* __restrict__ xb,
                                                          const float2* __restrict__ sqlab,
                                                          unsigned int* __restrict__ pos2,
                                                          unsigned int* __restrict__ neg2) {
  __shared__ __align__(16) unsigned short Us[4096 * 8];  // 64KB: A staging, then B dbuf
  __shared__ __align__(16) float2 sl_s[1024];            // 8KB (sq,label) for this col split
  __shared__ int lab_s[128];

  const int t = threadIdx.x;   // 0..511
  const int lane = t & 63;
  const int w = t >> 6;
  const int wr = w >> 2, wc = w & 3;  // 2 row-halves x 4 col-quarters
  const int c_l = lane & 15;
  const int kq_l = lane >> 4;
  const int rows0 = blockIdx.x * 128;
  const int cbase = blockIdx.y * (Nn / NSPLIT);

  // ---- stage A (both K halves) into Us; stage sl_s + labels ----
  stage_half(xb, rows0, 0, Us, t);
  stage_half(xb, rows0, 1, Us + 2048 * 8, t);
  sl_s[t] = sqlab[cbase + t];
  sl_s[512 + t] = sqlab[cbase + 512 + t];
  if (t < 128) lab_s[t] = __float_as_int(sqlab[rows0 + t].y);
  __syncthreads();  // A staged (implicit vmcnt(0))

  // ---- A fragments -> registers (forced residency: Us gets overwritten by B dbuf) ----
  const short8* Uv = (const short8*)Us;
  short8 af[32];
#pragma unroll
  for (int k2 = 0; k2 < 8; ++k2)
#pragma unroll
    for (int m = 0; m < 4; ++m) {
      const int kqf = k2 * 4 + kq_l;
      const int rl = wr * 64 + m * 16 + c_l;
      af[k2 * 4 + m] = Uv[(kqf >> 4) * 2048 + rl * 16 + ((kqf & 15) ^ (rl & 15))];
    }
  int labp[8];
#pragma unroll
  for (int m = 0; m < 4; ++m)
#pragma unroll
    for (int pp = 0; pp < 2; ++pp) {
      const int r0 = wr * 64 + m * 16 + kq_l * 4 + 2 * pp;
      labp[m * 2 + pp] = (lab_s[r0] & 0xffff) | (lab_s[r0 + 1] << 16);
    }
  __syncthreads();  // af/lab reads done before B dbuf overwrites Us

  unsigned short* Bs0 = Us;
  unsigned short* Bs1 = Us + 2048 * 8;
  const short8* Bv0 = (const short8*)Bs0;
  const short8* Bv1 = (const short8*)Bs1;

  stage_half(xb, cbase, 0, Bs0, t);  // prefetch first half-tile

  const int cc0 = wc * 32 + c_l;
  const int cc1 = wc * 32 + 16 + c_l;
  float pmax[16], nmin[16];
#pragma unroll
  for (int i = 0; i < 16; ++i) { pmax[i] = -INFINITY; nmin[i] = INFINITY; }

  f32x4 accA[4][2], accB[4][2];
  // peel ct=0 (no previous epilogue)
  do_ct<false>(accA, accB, 0, cbase, Bv0, Bv1, Bs0, Bs1, xb, af, labp, sl_s, pmax, nmin, t, cc0, cc1, kq_l);
#pragma unroll 1
  for (int k = 0; k < 3; ++k) {
    do_ct<true>(accB, accA, 2 * k + 1, cbase, Bv0, Bv1, Bs0, Bs1, xb, af, labp, sl_s, pmax, nmin, t, cc0, cc1, kq_l);
    do_ct<true>(accA, accB, 2 * k + 2, cbase, Bv0, Bv1, Bs0, Bs1, xb, af, labp, sl_s, pmax, nmin, t, cc0, cc1, kq_l);
  }
  do_ct<true>(accB, accA, 7, cbase, Bv0, Bv1, Bs0, Bs1, xb, af, labp, sl_s, pmax, nmin, t, cc0, cc1, kq_l);
  // final epilogue for ct=7
  epi_half<0>(accB, 7, sl_s, labp, pmax, nmin, cc0, cc1);
  epi_half<1>(accB, 7, sl_s, labp, pmax, nmin, cc0, cc1);

  // ---- reduce over 16 col-lanes, 2 atomics per row ----
#pragma unroll
  for (int i = 0; i < 16; ++i) {
    float p = pmax[i], nn2 = nmin[i];
#pragma unroll
    for (int off = 1; off < 16; off <<= 1) {
      p = fmaxf(p, __shfl_xor(p, off));
      nn2 = fminf(nn2, __shfl_xor(nn2, off));
    }
    if (c_l == 0) {
      const int rowg = rows0 + wr * 64 + (i >> 2) * 16 + kq_l * 4 + (i & 3);
      atomicMax(&pos2[rowg], enc_ord(p));
      atomicMin(&neg2[rowg], enc_ord(nn2));
    }
  }
}

// ---------------- K2a: hv + global extremes (parallel) ----------------
__global__ __launch_bounds__(512) void finalize_a_kernel(const float2* __restrict__ sqlab,
                                                         const unsigned int* __restrict__ pos2,
                                                         const unsigned int* __restrict__ neg2,
                                                         float* __restrict__ hv_g,
                                                         unsigned int* __restrict__ gmm) {
  const int i = blockIdx.x * 512 + threadIdx.x;
  const int lane = threadIdx.x & 63;
  const float s = sqlab[i].x;
  const float p2 = fmaxf(s + dec_ord(pos2[i]), 1e-12f);
  const float n2 = fmaxf(s + dec_ord(neg2[i]), 1e-12f);
  const float hv = sqrtf(p2) - sqrtf(n2);
  hv_g[i] = hv;
  float lmax = hv, lmin = hv;
#pragma unroll
  for (int off = 32; off >= 1; off >>= 1) {
    lmax = fmaxf(lmax, __shfl_xor(lmax, off));
    lmin = fminf(lmin, __shfl_xor(lmin, off));
  }
  if (lane == 0) {
    atomicMax(&gmm[0], enc_ord(lmax));
    atomicMin(&gmm[1], enc_ord(lmin));
  }
}

// ---------------- K2b: per-block histogram + per-bin hv sums (parallel) ----------------
__global__ __launch_bounds__(512) void finalize_b_kernel(const float* __restrict__ hv_g,
                                                         const unsigned int* __restrict__ gmm,
                                                         float* __restrict__ ghist,
                                                         float* __restrict__ ghsum) {
  __shared__ float hist_s[NBINS];
  __shared__ float hsum_s[NBINS];
  const int t = threadIdx.x;
  if (t < NBINS) { hist_s[t] = 0.0f; hsum_s[t] = 0.0f; }
  const float maxv = fmaxf(dec_ord(gmm[0]), 2.0f);
  const float minv = fminf(dec_ord(gmm[1]), -2.0f);
  const float bw = (maxv - minv) / (float)(NBINS - 1);
  __syncthreads();

  const int i = blockIdx.x * 512 + t;
  const float hv = hv_g[i];
  int lo = (int)floorf((hv - minv) / bw);
  lo = min(max(lo, 0), NBINS - 1);
  const int hi = min(lo + 1, NBINS - 1);
  const float alpha = 1.0f - (hv - minv - (float)lo * bw) / bw;
  atomicAdd(&hist_s[lo], alpha);
  atomicAdd(&hist_s[hi], 1.0f - alpha);
  atomicAdd(&hsum_s[lo], hv);  // weight uses bin_idx = lo (same floor+clip)
  __syncthreads();

  if (t < NBINS) {
    atomicAdd(&ghist[t], hist_s[t]);
    atomicAdd(&ghsum[t], hsum_s[t]);
  }
}

// ---------------- K2c: cdf + loss (one wave) ----------------
__global__ __launch_bounds__(64) void finalize_c_kernel(const float* __restrict__ ghist,
                                                        const float* __restrict__ ghsum,
                                                        float* __restrict__ out) {
  const int t = threadIdx.x;
  const float h = ghist[t];
  float total = h;
#pragma unroll
  for (int off = 32; off >= 1; off >>= 1) total += __shfl_xor(total, off);
  const float hn = h / (total + 1e-6f);
  float s2 = hn;
#pragma unroll
  for (int off = 32; off >= 1; off >>= 1) s2 += __shfl_xor(s2, off);
  const float pdf = hn / s2;
  float c = pdf;
#pragma unroll
  for (int off = 1; off < 64; off <<= 1) {
    const float u = __shfl_up(c, off);
    if (t >= off) c += u;
  }
  float acc = c * ghsum[t];
#pragma unroll
  for (int off = 32; off >= 1; off >>= 1) acc += __shfl_xor(acc, off);
  if (t == 0) out[0] = acc / (float)Nn;
}

// ---------------- launch ----------------
extern "C" void kernel_launch(void* const* d_in, const int* in_sizes, int n_in,
                              void* d_out, int out_size, void* d_ws, size_t ws_size,
                              hipStream_t stream) {
  const float* x = (const float*)d_in[0];
  const int* targets = (const int*)d_in[1];
  float* out = (float*)d_out;

  char* p = (char*)d_ws;
  unsigned short* xb = (unsigned short*)p;  p += (size_t)Nn * Dd * 2;  // 4MB
  float2* sqlab = (float2*)p;               p += (size_t)Nn * 8;
  unsigned int* pos2 = (unsigned int*)p;    p += (size_t)Nn * 4;
  unsigned int* neg2 = (unsigned int*)p;    p += (size_t)Nn * 4;
  float* hv_g = (float*)p;                  p += (size_t)Nn * 4;
  unsigned int* gmm = (unsigned int*)p;     p += 64;
  float* ghist = (float*)p;                 p += NBINS * 4;
  float* ghsum = (float*)p;

  prep_kernel<<<Nn / 4, 256, 0, stream>>>(x, targets, xb, sqlab, pos2, neg2, gmm, ghist, ghsum);
  pairwise_kernel<<<dim3(Nn / 128, NSPLIT), 512, 0, stream>>>(xb, sqlab, pos2, neg2);
  finalize_a_kernel<<<Nn / 512, 512, 0, stream>>>(sqlab, pos2, neg2, hv_g, gmm);
  finalize_b_kernel<<<Nn / 512, 512, 0, stream>>>(hv_g, gmm, ghist, ghsum);
  finalize_c_kernel<<<1, 64, 0, stream>>>(ghist, ghsum, out);
}

// Round 10
// 74.732 us; speedup vs baseline: 5.1284x; 2.4439x over previous
//
#include <hip/hip_runtime.h>
#include <math.h>

#define Nn 8192
#define Dd 256
#define NBINS 64
#define NSPLIT 8

typedef __attribute__((ext_vector_type(8))) short short8;
typedef __attribute__((ext_vector_type(4))) float f32x4;

#define GLOAD16(g, l)                                                        \
  __builtin_amdgcn_global_load_lds(                                          \
      (const __attribute__((address_space(1))) void*)(g),                    \
      (__attribute__((address_space(3))) void*)(l), 16, 0, 0)

static __device__ __forceinline__ unsigned short f2bf(float f) {
  unsigned int u = __float_as_uint(f);
  u = (u + 0x7fffu + ((u >> 16) & 1u)) >> 16;  // RNE
  return (unsigned short)u;
}
// order-preserving bijection float -> uint (atomicMax/Min on uint handles negatives)
static __device__ __forceinline__ unsigned int enc_ord(float f) {
  unsigned int u = __float_as_uint(f);
  return (u & 0x80000000u) ? ~u : (u | 0x80000000u);
}
static __device__ __forceinline__ float dec_ord(unsigned int u) {
  unsigned int b2 = (u & 0x80000000u) ? (u ^ 0x80000000u) : ~u;
  return __uint_as_float(b2);
}

// ---------------- K0: bf16 cast + fused (norm,label) + init accumulators ----------------
__global__ __launch_bounds__(256) void prep_kernel(const float* __restrict__ x,
                                                   const int* __restrict__ lab,
                                                   unsigned short* __restrict__ xb,
                                                   float2* __restrict__ sqlab,
                                                   unsigned int* __restrict__ pos2,
                                                   unsigned int* __restrict__ neg2,
                                                   unsigned int* __restrict__ gmm,
                                                   float* __restrict__ ghist,
                                                   float* __restrict__ ghsum) {
  const int w = threadIdx.x >> 6;
  const int lane = threadIdx.x & 63;
  const int row = blockIdx.x * 4 + w;
  const float4 v = *(const float4*)(x + (size_t)row * Dd + lane * 4);
  ushort4 b;
  b.x = f2bf(v.x); b.y = f2bf(v.y); b.z = f2bf(v.z); b.w = f2bf(v.w);
  *(ushort4*)(xb + (size_t)row * Dd + lane * 4) = b;
  float s = v.x * v.x + v.y * v.y + v.z * v.z + v.w * v.w;
#pragma unroll
  for (int off = 32; off >= 1; off >>= 1) s += __shfl_xor(s, off);
  if (lane == 0) {
    sqlab[row] = make_float2(s, __int_as_float(lab[row]));
    pos2[row] = 0x007fffffu;  // enc_ord(-inf)
    neg2[row] = 0xff800000u;  // enc_ord(+inf)
  }
  if (blockIdx.x == 0 && threadIdx.x < NBINS) {
    ghist[threadIdx.x] = 0.0f;
    ghsum[threadIdx.x] = 0.0f;
    if (threadIdx.x == 0) { gmm[0] = 0x007fffffu; gmm[1] = 0xff800000u; }
  }
}

// stage one A half-K tile (128 rows x 128 k = 32KB), XOR chunk placement, 256 threads
static __device__ __forceinline__ void stage_a(const unsigned short* __restrict__ xb,
                                               int r0, int hh, unsigned short* buf, int t) {
#pragma unroll
  for (int i = 0; i < 8; ++i) {
    const int c = i * 256 + t;          // 0..2047
    const int col = c >> 4;             // 0..127
    const int kq = (c & 15) ^ (col & 15);
    GLOAD16(xb + (size_t)(r0 + col) * Dd + hh * 128 + kq * 8, buf + (size_t)c * 8);
  }
}
// stage one B half-K tile (64 cols x 128 k = 16KB), XOR chunk placement, 256 threads
static __device__ __forceinline__ void stage_b(const unsigned short* __restrict__ xb,
                                               int c0, int hh, unsigned short* buf, int t) {
#pragma unroll
  for (int i = 0; i < 4; ++i) {
    const int c = i * 256 + t;          // 0..1023
    const int col = c >> 4;             // 0..63
    const int kq = (c & 15) ^ (col & 15);
    GLOAD16(xb + (size_t)(c0 + col) * Dd + hh * 128 + kq * 8, buf + (size_t)c * 8);
  }
}

// ---------------- K1: MFMA Gram + fused masked max/min ----------------
// 256-thread blocks (4 waves), wave tile 64x32, ct tile 128x64, 16 ct per col-split.
// Same per-wave register shape as the proven r5 kernel (af[32], acc[4][2]) => no spill,
// but 2 blocks/CU co-resident with INDEPENDENT barrier domains: while one block drains
// its stage at __syncthreads, the other feeds the MFMA pipe (m114 overlap).
__global__ __launch_bounds__(256, 2) void pairwise_kernel(const unsigned short* __restrict__ xb,
                                                          const float2* __restrict__ sqlab,
                                                          unsigned int* __restrict__ pos2,
                                                          unsigned int* __restrict__ neg2) {
  __shared__ __align__(16) unsigned short Us[4096 * 8];  // 64KB: A staging, then B dbuf (2x16KB)
  __shared__ __align__(16) float2 sl_s[1024];            // 8KB (sq,label) for this col split
  __shared__ int lab_s[128];

  const int t = threadIdx.x;   // 0..255
  const int lane = t & 63;
  const int w = t >> 6;        // 0..3
  const int wr = w >> 1;       // 0..1 (row half)
  const int wc = w & 1;        // 0..1 (col half of 64)
  const int c_l = lane & 15;
  const int kq_l = lane >> 4;
  const int rows0 = blockIdx.x * 128;
  const int cbase = blockIdx.y * (Nn / NSPLIT);

  // ---- stage A (both K halves) into Us; stage sl_s + labels ----
  stage_a(xb, rows0, 0, Us, t);
  stage_a(xb, rows0, 1, Us + 2048 * 8, t);
#pragma unroll
  for (int i = 0; i < 4; ++i) sl_s[i * 256 + t] = sqlab[cbase + i * 256 + t];
  if (t < 128) lab_s[t] = __float_as_int(sqlab[rows0 + t].y);
  __syncthreads();  // A staged (implicit vmcnt(0))

  // ---- A fragments -> registers (forced residency: Us gets overwritten by B dbuf) ----
  const short8* Uv = (const short8*)Us;
  short8 af[32];
#pragma unroll
  for (int k2 = 0; k2 < 8; ++k2)
#pragma unroll
    for (int m = 0; m < 4; ++m) {
      const int kqf = k2 * 4 + kq_l;               // global k-octet 0..31
      const int rl = wr * 64 + m * 16 + c_l;       // local row 0..127
      af[k2 * 4 + m] = Uv[(kqf >> 4) * 2048 + rl * 16 + ((kqf & 15) ^ (rl & 15))];
    }
  int labp[8];
#pragma unroll
  for (int m = 0; m < 4; ++m)
#pragma unroll
    for (int pp = 0; pp < 2; ++pp) {
      const int r0 = wr * 64 + m * 16 + kq_l * 4 + 2 * pp;
      labp[m * 2 + pp] = (lab_s[r0] & 0xffff) | (lab_s[r0 + 1] << 16);
    }
  __syncthreads();  // af/lab reads done before B dbuf overwrites Us

  unsigned short* Bs0 = Us;               // 16KB
  unsigned short* Bs1 = Us + 1024 * 8;    // 16KB
  const short8* Bv0 = (const short8*)Bs0;
  const short8* Bv1 = (const short8*)Bs1;

  stage_b(xb, cbase, 0, Bs0, t);  // prefetch first half-tile

  const int cc0 = wc * 32 + c_l;        // local col 0..47
  const int cc1 = wc * 32 + 16 + c_l;   // local col 16..63
  float pmax[16], nmin[16];
#pragma unroll
  for (int i = 0; i < 16; ++i) { pmax[i] = -INFINITY; nmin[i] = INFINITY; }

#pragma unroll 1
  for (int ct = 0; ct < 16; ++ct) {
    const int c0 = cbase + ct * 64;
    f32x4 acc[4][2];
#pragma unroll
    for (int m = 0; m < 4; ++m)
#pragma unroll
      for (int n = 0; n < 2; ++n) acc[m][n] = (f32x4){0.f, 0.f, 0.f, 0.f};

    // ---- half 0: compute Bs0, prefetch Bs1 ----
    __syncthreads();  // Bs0 staged (loads issued one phase ago); WAR-protects Bs1
    stage_b(xb, c0, 1, Bs1, t);
#pragma unroll
    for (int ks = 0; ks < 4; ++ks) {
      const short8 bf0 = Bv0[cc0 * 16 + ((ks * 4 + kq_l) ^ (cc0 & 15))];
      const short8 bf1 = Bv0[cc1 * 16 + ((ks * 4 + kq_l) ^ (cc1 & 15))];
#pragma unroll
      for (int m = 0; m < 4; ++m) {
        acc[m][0] = __builtin_amdgcn_mfma_f32_16x16x32_bf16(af[ks * 4 + m], bf0, acc[m][0], 0, 0, 0);
        acc[m][1] = __builtin_amdgcn_mfma_f32_16x16x32_bf16(af[ks * 4 + m], bf1, acc[m][1], 0, 0, 0);
      }
    }

    // ---- half 1: compute Bs1, prefetch next ct's Bs0 ----
    __syncthreads();  // Bs1 staged; WAR-protects Bs0
    if (ct < 15) stage_b(xb, c0 + 64, 0, Bs0, t);
#pragma unroll
    for (int ks = 0; ks < 4; ++ks) {
      const short8 bf0 = Bv1[cc0 * 16 + ((ks * 4 + kq_l) ^ (cc0 & 15))];
      const short8 bf1 = Bv1[cc1 * 16 + ((ks * 4 + kq_l) ^ (cc1 & 15))];
#pragma unroll
      for (int m = 0; m < 4; ++m) {
        acc[m][0] = __builtin_amdgcn_mfma_f32_16x16x32_bf16(af[(4 + ks) * 4 + m], bf0, acc[m][0], 0, 0, 0);
        acc[m][1] = __builtin_amdgcn_mfma_f32_16x16x32_bf16(af[(4 + ks) * 4 + m], bf1, acc[m][1], 0, 0, 0);
      }
    }

    // ---- epilogue: masked running max/min on g = sq_c - 2*acc ----
    {
      const float2 sl0 = sl_s[ct * 64 + cc0];
      const float2 sl1 = sl_s[ct * 64 + cc1];
#pragma unroll
      for (int n = 0; n < 2; ++n) {
        const float sc = (n == 0) ? sl0.x : sl1.x;
        const int lc = __float_as_int((n == 0) ? sl0.y : sl1.y);
#pragma unroll
        for (int idx = 0; idx < 16; ++idx) {
          const int m = idx >> 2, q = idx & 3;
          const float g = fmaf(-2.0f, acc[m][n][q], sc);
          const int lr = (labp[idx >> 1] >> ((idx & 1) * 16)) & 0xffff;
          const bool same = (lr == lc);
          pmax[idx] = same ? fmaxf(pmax[idx], g) : pmax[idx];
          nmin[idx] = same ? nmin[idx] : fminf(nmin[idx], g);
        }
      }
    }
  }

  // ---- reduce over 16 col-lanes, 2 atomics per row ----
#pragma unroll
  for (int i = 0; i < 16; ++i) {
    float p = pmax[i], nn2 = nmin[i];
#pragma unroll
    for (int off = 1; off < 16; off <<= 1) {
      p = fmaxf(p, __shfl_xor(p, off));
      nn2 = fminf(nn2, __shfl_xor(nn2, off));
    }
    if (c_l == 0) {
      const int rowg = rows0 + wr * 64 + (i >> 2) * 16 + kq_l * 4 + (i & 3);
      atomicMax(&pos2[rowg], enc_ord(p));
      atomicMin(&neg2[rowg], enc_ord(nn2));
    }
  }
}

// ---------------- K2a: hv + global extremes (parallel) ----------------
__global__ __launch_bounds__(512) void finalize_a_kernel(const float2* __restrict__ sqlab,
                                                         const unsigned int* __restrict__ pos2,
                                                         const unsigned int* __restrict__ neg2,
                                                         float* __restrict__ hv_g,
                                                         unsigned int* __restrict__ gmm) {
  const int i = blockIdx.x * 512 + threadIdx.x;
  const int lane = threadIdx.x & 63;
  const float s = sqlab[i].x;
  const float p2 = fmaxf(s + dec_ord(pos2[i]), 1e-12f);
  const float n2 = fmaxf(s + dec_ord(neg2[i]), 1e-12f);
  const float hv = sqrtf(p2) - sqrtf(n2);
  hv_g[i] = hv;
  float lmax = hv, lmin = hv;
#pragma unroll
  for (int off = 32; off >= 1; off >>= 1) {
    lmax = fmaxf(lmax, __shfl_xor(lmax, off));
    lmin = fminf(lmin, __shfl_xor(lmin, off));
  }
  if (lane == 0) {
    atomicMax(&gmm[0], enc_ord(lmax));
    atomicMin(&gmm[1], enc_ord(lmin));
  }
}

// ---------------- K2b: per-block histogram + per-bin hv sums (parallel) ----------------
__global__ __launch_bounds__(512) void finalize_b_kernel(const float* __restrict__ hv_g,
                                                         const unsigned int* __restrict__ gmm,
                                                         float* __restrict__ ghist,
                                                         float* __restrict__ ghsum) {
  __shared__ float hist_s[NBINS];
  __shared__ float hsum_s[NBINS];
  const int t = threadIdx.x;
  if (t < NBINS) { hist_s[t] = 0.0f; hsum_s[t] = 0.0f; }
  const float maxv = fmaxf(dec_ord(gmm[0]), 2.0f);
  const float minv = fminf(dec_ord(gmm[1]), -2.0f);
  const float bw = (maxv - minv) / (float)(NBINS - 1);
  __syncthreads();

  const int i = blockIdx.x * 512 + t;
  const float hv = hv_g[i];
  int lo = (int)floorf((hv - minv) / bw);
  lo = min(max(lo, 0), NBINS - 1);
  const int hi = min(lo + 1, NBINS - 1);
  const float alpha = 1.0f - (hv - minv - (float)lo * bw) / bw;
  atomicAdd(&hist_s[lo], alpha);
  atomicAdd(&hist_s[hi], 1.0f - alpha);
  atomicAdd(&hsum_s[lo], hv);  // weight uses bin_idx = lo (same floor+clip)
  __syncthreads();

  if (t < NBINS) {
    atomicAdd(&ghist[t], hist_s[t]);
    atomicAdd(&ghsum[t], hsum_s[t]);
  }
}

// ---------------- K2c: cdf + loss (one wave) ----------------
__global__ __launch_bounds__(64) void finalize_c_kernel(const float* __restrict__ ghist,
                                                        const float* __restrict__ ghsum,
                                                        float* __restrict__ out) {
  const int t = threadIdx.x;
  const float h = ghist[t];
  float total = h;
#pragma unroll
  for (int off = 32; off >= 1; off >>= 1) total += __shfl_xor(total, off);
  const float hn = h / (total + 1e-6f);
  float s2 = hn;
#pragma unroll
  for (int off = 32; off >= 1; off >>= 1) s2 += __shfl_xor(s2, off);
  const float pdf = hn / s2;
  float c = pdf;
#pragma unroll
  for (int off = 1; off < 64; off <<= 1) {
    const float u = __shfl_up(c, off);
    if (t >= off) c += u;
  }
  float acc = c * ghsum[t];
#pragma unroll
  for (int off = 32; off >= 1; off >>= 1) acc += __shfl_xor(acc, off);
  if (t == 0) out[0] = acc / (float)Nn;
}

// ---------------- launch ----------------
extern "C" void kernel_launch(void* const* d_in, const int* in_sizes, int n_in,
                              void* d_out, int out_size, void* d_ws, size_t ws_size,
                              hipStream_t stream) {
  const float* x = (const float*)d_in[0];
  const int* targets = (const int*)d_in[1];
  float* out = (float*)d_out;

  char* p = (char*)d_ws;
  unsigned short* xb = (unsigned short*)p;  p += (size_t)Nn * Dd * 2;  // 4MB
  float2* sqlab = (float2*)p;               p += (size_t)Nn * 8;
  unsigned int* pos2 = (unsigned int*)p;    p += (size_t)Nn * 4;
  unsigned int* neg2 = (unsigned int*)p;    p += (size_t)Nn * 4;
  float* hv_g = (float*)p;                  p += (size_t)Nn * 4;
  unsigned int* gmm = (unsigned int*)p;     p += 64;
  float* ghist = (float*)p;                 p += NBINS * 4;
  float* ghsum = (float*)p;

  prep_kernel<<<Nn / 4, 256, 0, stream>>>(x, targets, xb, sqlab, pos2, neg2, gmm, ghist, ghsum);
  pairwise_kernel<<<dim3(Nn / 128, NSPLIT), 256, 0, stream>>>(xb, sqlab, pos2, neg2);
  finalize_a_kernel<<<Nn / 512, 512, 0, stream>>>(sqlab, pos2, neg2, hv_g, gmm);
  finalize_b_kernel<<<Nn / 512, 512, 0, stream>>>(hv_g, gmm, ghist, ghsum);
  finalize_c_kernel<<<1, 64, 0, stream>>>(ghist, ghsum, out);
}

// Round 11
// 64.514 us; speedup vs baseline: 5.9407x; 1.1584x over previous
//
#include <hip/hip_runtime.h>
#include <math.h>

#define Nn 8192
#define Dd 256
#define NBINS 64
#define NSPLIT 8

typedef __attribute__((ext_vector_type(8))) short short8;
typedef __attribute__((ext_vector_type(4))) float f32x4;

#define GLOAD16(g, l)                                                        \
  __builtin_amdgcn_global_load_lds(                                          \
      (const __attribute__((address_space(1))) void*)(g),                    \
      (__attribute__((address_space(3))) void*)(l), 16, 0, 0)

static __device__ __forceinline__ unsigned short f2bf(float f) {
  unsigned int u = __float_as_uint(f);
  u = (u + 0x7fffu + ((u >> 16) & 1u)) >> 16;  // RNE
  return (unsigned short)u;
}
// order-preserving bijection float -> uint (atomicMax/Min on uint handles negatives)
static __device__ __forceinline__ unsigned int enc_ord(float f) {
  unsigned int u = __float_as_uint(f);
  return (u & 0x80000000u) ? ~u : (u | 0x80000000u);
}
static __device__ __forceinline__ float dec_ord(unsigned int u) {
  unsigned int b2 = (u & 0x80000000u) ? (u ^ 0x80000000u) : ~u;
  return __uint_as_float(b2);
}

// ---------------- K0: bf16 cast + fused (norm,label) + init accumulators ----------------
__global__ __launch_bounds__(256) void prep_kernel(const float* __restrict__ x,
                                                   const int* __restrict__ lab,
                                                   unsigned short* __restrict__ xb,
                                                   float2* __restrict__ sqlab,
                                                   unsigned int* __restrict__ pos2,
                                                   unsigned int* __restrict__ neg2,
                                                   unsigned int* __restrict__ gmm,
                                                   float* __restrict__ ghist,
                                                   float* __restrict__ ghsum) {
  const int w = threadIdx.x >> 6;
  const int lane = threadIdx.x & 63;
  const int row = blockIdx.x * 4 + w;
  const float4 v = *(const float4*)(x + (size_t)row * Dd + lane * 4);
  ushort4 b;
  b.x = f2bf(v.x); b.y = f2bf(v.y); b.z = f2bf(v.z); b.w = f2bf(v.w);
  *(ushort4*)(xb + (size_t)row * Dd + lane * 4) = b;
  float s = v.x * v.x + v.y * v.y + v.z * v.z + v.w * v.w;
#pragma unroll
  for (int off = 32; off >= 1; off >>= 1) s += __shfl_xor(s, off);
  if (lane == 0) {
    sqlab[row] = make_float2(s, __int_as_float(lab[row]));
    pos2[row] = 0x007fffffu;  // enc_ord(-inf)
    neg2[row] = 0xff800000u;  // enc_ord(+inf)
  }
  if (blockIdx.x == 0 && threadIdx.x < NBINS) {
    ghist[threadIdx.x] = 0.0f;
    ghsum[threadIdx.x] = 0.0f;
    if (threadIdx.x == 0) { gmm[0] = 0x007fffffu; gmm[1] = 0xff800000u; }
  }
}

// stage one A half-K tile (128 rows x 128 k = 32KB), XOR chunk placement, 256 threads
static __device__ __forceinline__ void stage_a(const unsigned short* __restrict__ xb,
                                               int r0, int hh, unsigned short* buf, int t) {
#pragma unroll
  for (int i = 0; i < 8; ++i) {
    const int c = i * 256 + t;          // 0..2047
    const int col = c >> 4;             // 0..127
    const int kq = (c & 15) ^ (col & 15);
    GLOAD16(xb + (size_t)(r0 + col) * Dd + hh * 128 + kq * 8, buf + (size_t)c * 8);
  }
}
// stage one B half-K tile (64 cols x 128 k = 16KB), XOR chunk placement, 256 threads
// exactly 4 global_load_lds per thread -> vmcnt arithmetic below counts in units of 4
static __device__ __forceinline__ void stage_b(const unsigned short* __restrict__ xb,
                                               int c0, int hh, unsigned short* buf, int t) {
#pragma unroll
  for (int i = 0; i < 4; ++i) {
    const int c = i * 256 + t;          // 0..1023
    const int col = c >> 4;             // 0..63
    const int kq = (c & 15) ^ (col & 15);
    GLOAD16(xb + (size_t)(c0 + col) * Dd + hh * 128 + kq * 8, buf + (size_t)c * 8);
  }
}

// ---------------- K1: MFMA Gram + fused masked max/min (3-buffer ring, counted vmcnt) ----------------
// r10 geometry (4 waves, 64x32 wave tiles, 128x64 ct tiles, 2 blocks/CU), but the per-phase
// __syncthreads (which drains vmcnt(0) -> m233's ~2200cy/phase stall) is replaced by
// s_waitcnt vmcnt(4) + raw s_barrier: each phase stages the half-tile needed TWO phases
// later, so drained loads are ~2 phases old and the 4 newest stay in flight (T3/T4).
// The K-loop contains no other VMEM ops, so vmcnt counts are exact.
__global__ __launch_bounds__(256, 2) void pairwise_kernel(const unsigned short* __restrict__ xb,
                                                          const float2* __restrict__ sqlab,
                                                          unsigned int* __restrict__ pos2,
                                                          unsigned int* __restrict__ neg2) {
  __shared__ __align__(16) unsigned short Us[4096 * 8];  // 64KB: A staging, then 3x16KB B ring
  __shared__ __align__(16) float2 sl_s[1024];            // 8KB (sq,label) for this col split
  __shared__ int lab_s[128];

  const int t = threadIdx.x;   // 0..255
  const int lane = t & 63;
  const int w = t >> 6;        // 0..3
  const int wr = w >> 1;       // 0..1 (row half)
  const int wc = w & 1;        // 0..1 (col half of 64)
  const int c_l = lane & 15;
  const int kq_l = lane >> 4;
  const int rows0 = blockIdx.x * 128;
  const int cbase = blockIdx.y * (Nn / NSPLIT);

  // ---- stage A (both K halves) into Us; stage sl_s + labels ----
  stage_a(xb, rows0, 0, Us, t);
  stage_a(xb, rows0, 1, Us + 2048 * 8, t);
#pragma unroll
  for (int i = 0; i < 4; ++i) sl_s[i * 256 + t] = sqlab[cbase + i * 256 + t];
  if (t < 128) lab_s[t] = __float_as_int(sqlab[rows0 + t].y);
  __syncthreads();  // full drain (one-time) — vmcnt starts clean after this

  // ---- A fragments -> registers (forced residency: Us gets overwritten by B ring) ----
  const short8* Uv = (const short8*)Us;
  short8 af[32];
#pragma unroll
  for (int k2 = 0; k2 < 8; ++k2)
#pragma unroll
    for (int m = 0; m < 4; ++m) {
      const int kqf = k2 * 4 + kq_l;               // global k-octet 0..31
      const int rl = wr * 64 + m * 16 + c_l;       // local row 0..127
      af[k2 * 4 + m] = Uv[(kqf >> 4) * 2048 + rl * 16 + ((kqf & 15) ^ (rl & 15))];
    }
  int labp[8];
#pragma unroll
  for (int m = 0; m < 4; ++m)
#pragma unroll
    for (int pp = 0; pp < 2; ++pp) {
      const int r0 = wr * 64 + m * 16 + kq_l * 4 + 2 * pp;
      labp[m * 2 + pp] = (lab_s[r0] & 0xffff) | (lab_s[r0 + 1] << 16);
    }
  __syncthreads();  // af/lab reads done before B ring overwrites Us

  unsigned short* const B0 = Us;               // 16KB each
  unsigned short* const B1 = Us + 1024 * 8;
  unsigned short* const B2 = Us + 2048 * 8;

  // prologue: ct0 half0 -> B0, ct0 half1 -> B1 (8 loads in flight)
  stage_b(xb, cbase, 0, B0, t);
  stage_b(xb, cbase, 1, B1, t);

  const int cc0 = wc * 32 + c_l;        // local col
  const int cc1 = wc * 32 + 16 + c_l;
  float pmax[16], nmin[16];
#pragma unroll
  for (int i = 0; i < 16; ++i) { pmax[i] = -INFINITY; nmin[i] = INFINITY; }

  int rA = 0;
#pragma unroll 1
  for (int ct = 0; ct < 16; ++ct) {
    const int rB = (rA == 2) ? 0 : rA + 1;
    const int rC = (rB == 2) ? 0 : rB + 1;
    unsigned short* const bufA = (rA == 0) ? B0 : ((rA == 1) ? B1 : B2);
    unsigned short* const bufB = (rB == 0) ? B0 : ((rB == 1) ? B1 : B2);
    unsigned short* const bufC = (rC == 0) ? B0 : ((rC == 1) ? B1 : B2);
    const int cnext = cbase + ((ct + 1) & 15) * 64;  // wraps at tail (dead stores keep count uniform)

    f32x4 acc[4][2];
#pragma unroll
    for (int m = 0; m < 4; ++m)
#pragma unroll
      for (int n = 0; n < 2; ++n) acc[m][n] = (f32x4){0.f, 0.f, 0.f, 0.f};

    // ---- even phase: consume bufA (k-half 0); stage ct+1 half0 -> bufC ----
    asm volatile("s_waitcnt vmcnt(4)" ::: "memory");  // bufA's 4 loads done; newest 4 in flight
    __builtin_amdgcn_s_barrier();                     // WAR: all waves done reading bufC's old data
    stage_b(xb, cnext, 0, bufC, t);
    {
      const short8* Bv = (const short8*)bufA;
#pragma unroll
      for (int ks = 0; ks < 4; ++ks) {
        const short8 bf0 = Bv[cc0 * 16 + ((ks * 4 + kq_l) ^ (cc0 & 15))];
        const short8 bf1 = Bv[cc1 * 16 + ((ks * 4 + kq_l) ^ (cc1 & 15))];
#pragma unroll
        for (int m = 0; m < 4; ++m) {
          acc[m][0] = __builtin_amdgcn_mfma_f32_16x16x32_bf16(af[ks * 4 + m], bf0, acc[m][0], 0, 0, 0);
          acc[m][1] = __builtin_amdgcn_mfma_f32_16x16x32_bf16(af[ks * 4 + m], bf1, acc[m][1], 0, 0, 0);
        }
      }
    }

    // ---- odd phase: consume bufB (k-half 1); stage ct+1 half1 -> bufA ----
    asm volatile("s_waitcnt vmcnt(4)" ::: "memory");  // bufB's 4 loads done
    __builtin_amdgcn_s_barrier();                     // WAR: all waves done reading bufA
    stage_b(xb, cnext, 1, bufA, t);
    {
      const short8* Bv = (const short8*)bufB;
#pragma unroll
      for (int ks = 0; ks < 4; ++ks) {
        const short8 bf0 = Bv[cc0 * 16 + ((ks * 4 + kq_l) ^ (cc0 & 15))];
        const short8 bf1 = Bv[cc1 * 16 + ((ks * 4 + kq_l) ^ (cc1 & 15))];
#pragma unroll
        for (int m = 0; m < 4; ++m) {
          acc[m][0] = __builtin_amdgcn_mfma_f32_16x16x32_bf16(af[(4 + ks) * 4 + m], bf0, acc[m][0], 0, 0, 0);
          acc[m][1] = __builtin_amdgcn_mfma_f32_16x16x32_bf16(af[(4 + ks) * 4 + m], bf1, acc[m][1], 0, 0, 0);
        }
      }
    }

    // ---- epilogue: masked running max/min on g = sq_c - 2*acc (overlaps in-flight loads) ----
    {
      const float2 sl0 = sl_s[ct * 64 + cc0];
      const float2 sl1 = sl_s[ct * 64 + cc1];
#pragma unroll
      for (int n = 0; n < 2; ++n) {
        const float sc = (n == 0) ? sl0.x : sl1.x;
        const int lc = __float_as_int((n == 0) ? sl0.y : sl1.y);
#pragma unroll
        for (int idx = 0; idx < 16; ++idx) {
          const int m = idx >> 2, q = idx & 3;
          const float g = fmaf(-2.0f, acc[m][n][q], sc);
          const int lr = (labp[idx >> 1] >> ((idx & 1) * 16)) & 0xffff;
          const bool same = (lr == lc);
          pmax[idx] = same ? fmaxf(pmax[idx], g) : pmax[idx];
          nmin[idx] = same ? nmin[idx] : fminf(nmin[idx], g);
        }
      }
    }
    rA = rC;
  }

  // ---- reduce over 16 col-lanes, 2 atomics per row ----
#pragma unroll
  for (int i = 0; i < 16; ++i) {
    float p = pmax[i], nn2 = nmin[i];
#pragma unroll
    for (int off = 1; off < 16; off <<= 1) {
      p = fmaxf(p, __shfl_xor(p, off));
      nn2 = fminf(nn2, __shfl_xor(nn2, off));
    }
    if (c_l == 0) {
      const int rowg = rows0 + wr * 64 + (i >> 2) * 16 + kq_l * 4 + (i & 3);
      atomicMax(&pos2[rowg], enc_ord(p));
      atomicMin(&neg2[rowg], enc_ord(nn2));
    }
  }
}

// ---------------- K2a: hv + global extremes (parallel) ----------------
__global__ __launch_bounds__(512) void finalize_a_kernel(const float2* __restrict__ sqlab,
                                                         const unsigned int* __restrict__ pos2,
                                                         const unsigned int* __restrict__ neg2,
                                                         float* __restrict__ hv_g,
                                                         unsigned int* __restrict__ gmm) {
  const int i = blockIdx.x * 512 + threadIdx.x;
  const int lane = threadIdx.x & 63;
  const float s = sqlab[i].x;
  const float p2 = fmaxf(s + dec_ord(pos2[i]), 1e-12f);
  const float n2 = fmaxf(s + dec_ord(neg2[i]), 1e-12f);
  const float hv = sqrtf(p2) - sqrtf(n2);
  hv_g[i] = hv;
  float lmax = hv, lmin = hv;
#pragma unroll
  for (int off = 32; off >= 1; off >>= 1) {
    lmax = fmaxf(lmax, __shfl_xor(lmax, off));
    lmin = fminf(lmin, __shfl_xor(lmin, off));
  }
  if (lane == 0) {
    atomicMax(&gmm[0], enc_ord(lmax));
    atomicMin(&gmm[1], enc_ord(lmin));
  }
}

// ---------------- K2b: per-block histogram + per-bin hv sums (parallel) ----------------
__global__ __launch_bounds__(512) void finalize_b_kernel(const float* __restrict__ hv_g,
                                                         const unsigned int* __restrict__ gmm,
                                                         float* __restrict__ ghist,
                                                         float* __restrict__ ghsum) {
  __shared__ float hist_s[NBINS];
  __shared__ float hsum_s[NBINS];
  const int t = threadIdx.x;
  if (t < NBINS) { hist_s[t] = 0.0f; hsum_s[t] = 0.0f; }
  const float maxv = fmaxf(dec_ord(gmm[0]), 2.0f);
  const float minv = fminf(dec_ord(gmm[1]), -2.0f);
  const float bw = (maxv - minv) / (float)(NBINS - 1);
  __syncthreads();

  const int i = blockIdx.x * 512 + t;
  const float hv = hv_g[i];
  int lo = (int)floorf((hv - minv) / bw);
  lo = min(max(lo, 0), NBINS - 1);
  const int hi = min(lo + 1, NBINS - 1);
  const float alpha = 1.0f - (hv - minv - (float)lo * bw) / bw;
  atomicAdd(&hist_s[lo], alpha);
  atomicAdd(&hist_s[hi], 1.0f - alpha);
  atomicAdd(&hsum_s[lo], hv);  // weight uses bin_idx = lo (same floor+clip)
  __syncthreads();

  if (t < NBINS) {
    atomicAdd(&ghist[t], hist_s[t]);
    atomicAdd(&ghsum[t], hsum_s[t]);
  }
}

// ---------------- K2c: cdf + loss (one wave) ----------------
__global__ __launch_bounds__(64) void finalize_c_kernel(const float* __restrict__ ghist,
                                                        const float* __restrict__ ghsum,
                                                        float* __restrict__ out) {
  const int t = threadIdx.x;
  const float h = ghist[t];
  float total = h;
#pragma unroll
  for (int off = 32; off >= 1; off >>= 1) total += __shfl_xor(total, off);
  const float hn = h / (total + 1e-6f);
  float s2 = hn;
#pragma unroll
  for (int off = 32; off >= 1; off >>= 1) s2 += __shfl_xor(s2, off);
  const float pdf = hn / s2;
  float c = pdf;
#pragma unroll
  for (int off = 1; off < 64; off <<= 1) {
    const float u = __shfl_up(c, off);
    if (t >= off) c += u;
  }
  float acc = c * ghsum[t];
#pragma unroll
  for (int off = 32; off >= 1; off >>= 1) acc += __shfl_xor(acc, off);
  if (t == 0) out[0] = acc / (float)Nn;
}

// ---------------- launch ----------------
extern "C" void kernel_launch(void* const* d_in, const int* in_sizes, int n_in,
                              void* d_out, int out_size, void* d_ws, size_t ws_size,
                              hipStream_t stream) {
  const float* x = (const float*)d_in[0];
  const int* targets = (const int*)d_in[1];
  float* out = (float*)d_out;

  char* p = (char*)d_ws;
  unsigned short* xb = (unsigned short*)p;  p += (size_t)Nn * Dd * 2;  // 4MB
  float2* sqlab = (float2*)p;               p += (size_t)Nn * 8;
  unsigned int* pos2 = (unsigned int*)p;    p += (size_t)Nn * 4;
  unsigned int* neg2 = (unsigned int*)p;    p += (size_t)Nn * 4;
  float* hv_g = (float*)p;                  p += (size_t)Nn * 4;
  unsigned int* gmm = (unsigned int*)p;     p += 64;
  float* ghist = (float*)p;                 p += NBINS * 4;
  float* ghsum = (float*)p;

  prep_kernel<<<Nn / 4, 256, 0, stream>>>(x, targets, xb, sqlab, pos2, neg2, gmm, ghist, ghsum);
  pairwise_kernel<<<dim3(Nn / 128, NSPLIT), 256, 0, stream>>>(xb, sqlab, pos2, neg2);
  finalize_a_kernel<<<Nn / 512, 512, 0, stream>>>(sqlab, pos2, neg2, hv_g, gmm);
  finalize_b_kernel<<<Nn / 512, 512, 0, stream>>>(hv_g, gmm, ghist, ghsum);
  finalize_c_kernel<<<1, 64, 0, stream>>>(ghist, ghsum, out);
}